// Round 4
// baseline (175.528 us; speedup 1.0000x reference)
//
#include <hip/hip_runtime.h>

#define BB 2
#define TT 2048
#define DD 1024
#define HH 16
#define DHD 64
#define MM (BB*TT)   // 4096

typedef __attribute__((ext_vector_type(8))) short short8;
typedef __attribute__((ext_vector_type(4))) float float4v;
typedef __attribute__((ext_vector_type(16))) float f32x16;
typedef unsigned short u16;

__device__ inline float bf2f(u16 u) {
    union { unsigned int i; float f; } v;
    v.i = ((unsigned int)u) << 16;
    return v.f;
}
__device__ inline u16 f2bf(float f) {
    union { float f; unsigned int i; } v;
    v.f = f;
    unsigned int x = v.i;
    unsigned int r = (x + 0x7fffu + ((x >> 16) & 1u)) >> 16;
    return (u16)r;
}
// truncating bf16 pair-pack (bit-identical to the old P-store path)
__device__ inline unsigned packtr(float x, float y) {
    union { float f; unsigned u; } a, b;
    a.f = x; b.f = y;
    return (a.u >> 16) | (b.u & 0xffff0000u);
}

// async 16B global->LDS (DMA, no VGPR round-trip)
__device__ inline void gl_lds16(const u16* g, u16* l) {
    __builtin_amdgcn_global_load_lds(
        (const __attribute__((address_space(1))) unsigned int*)g,
        (__attribute__((address_space(3))) unsigned int*)l, 16, 0, 0);
}

// ---------------- prep: fused x-cast (z==4) + weight cast/transpose (z<4) ----------------
__global__ __launch_bounds__(256) void prep_k(const float* __restrict__ x,
                                              const float* __restrict__ Wq,
                                              const float* __restrict__ Wk,
                                              const float* __restrict__ Wv,
                                              const float* __restrict__ Wo,
                                              u16* __restrict__ xb,
                                              u16* __restrict__ WT) {
    int tid = threadIdx.x;
    if (blockIdx.z == 4) {   // cast x: 1024 blocks x 1024 float4
        int bid = blockIdx.y * 32 + blockIdx.x;
#pragma unroll
        for (int k = 0; k < 4; k++) {
            int i = bid * 1024 + k * 256 + tid;
            float4v v = ((const float4v*)x)[i];
            ushort4 o;
            o.x = f2bf(v[0]); o.y = f2bf(v[1]); o.z = f2bf(v[2]); o.w = f2bf(v[3]);
            ((ushort4*)xb)[i] = o;
        }
        return;
    }
    __shared__ u16 t[32][33];
    int wsel = blockIdx.z;
    const float* W = (wsel == 0) ? Wq : (wsel == 1) ? Wk : (wsel == 2) ? Wv : Wo;
    u16* o = WT + (size_t)wsel * DD * DD;
    int k0 = blockIdx.y * 32, n0 = blockIdx.x * 32;
    int tx = tid & 31, ty = tid >> 5;   // 32 x 8
#pragma unroll
    for (int i = 0; i < 4; i++) {
        int k = ty + i * 8;
        t[k][tx] = f2bf(W[(size_t)(k0 + k) * DD + n0 + tx]);
    }
    __syncthreads();
#pragma unroll
    for (int i = 0; i < 4; i++) {
        int n = ty + i * 8;
        o[(size_t)(n0 + n) * DD + k0 + tx] = t[tx][n];
    }
}

// ---------------- GEMM: global_load_lds staging (m97 structure) ----------------
template <int MODE, int TM, int TN, int BK>
__global__ __launch_bounds__(256) void gemm_k(const u16* __restrict__ A,
                                              const u16* __restrict__ WT0,
                                              void* __restrict__ outp) {
    const int K = DD;
    const int MT = TM / 32, NT = TN / 32;
    const int NS = (TM + TN) * (BK / 8) / 256;
    const int CPR = BK / 8;

    int z = blockIdx.z;
    const u16* WT = WT0 + (size_t)z * DD * DD;
    int n0 = blockIdx.x * TN, m0 = blockIdx.y * TM;

    __shared__ u16 S[(TM + TN) * BK];

    int tid = threadIdx.x;
    int lane = tid & 63, w = tid >> 6;
    int wm = (w >> 1) * (TM / 2), wn = (w & 1) * (TN / 2);
    int quad = lane >> 4, l16 = lane & 15;

    const u16* gp[NS];
    u16* lp[NS];
#pragma unroll
    for (int j = 0; j < NS; j++) {
        int cid = tid + j * 256;
        int r = cid / CPR, c = cid % CPR;
        lp[j] = S + (size_t)cid * 8;                      // linear LDS dest
        gp[j] = (r < TM ? A + (size_t)(m0 + r) * K
                        : WT + (size_t)(n0 + r - TM) * K) + ((c ^ (r & 7)) * 8);
    }
    int swz = l16 & 7;

    float4v acc[MT][NT];
#pragma unroll
    for (int i = 0; i < MT; i++)
#pragma unroll
        for (int j = 0; j < NT; j++) acc[i][j] = (float4v)(0.0f);

    const int NK = K / BK;
#pragma unroll 1
    for (int ki = 0; ki < NK; ki++) {
        __syncthreads();    // prev compute's S reads done
#pragma unroll
        for (int j = 0; j < NS; j++)
            gl_lds16(gp[j] + ki * BK, lp[j]);
        __syncthreads();    // barrier drain (vmcnt 0) publishes S

#pragma unroll
        for (int ks = 0; ks < BK / 32; ks++) {
            int cq = ((ks * 4 + quad) ^ swz) * 8;
            short8 a[MT], b[NT];
#pragma unroll
            for (int mt = 0; mt < MT; mt++)
                a[mt] = *(const short8*)&S[(wm + mt * 16 + l16) * BK + cq];
#pragma unroll
            for (int nt = 0; nt < NT; nt++)
                b[nt] = *(const short8*)&S[(TM + wn + nt * 16 + l16) * BK + cq];
#pragma unroll
            for (int mt = 0; mt < MT; mt++)
#pragma unroll
                for (int nt = 0; nt < NT; nt++)
                    acc[mt][nt] = __builtin_amdgcn_mfma_f32_16x16x32_bf16(
                        a[mt], b[nt], acc[mt][nt], 0, 0, 0);
        }
    }

#pragma unroll
    for (int mt = 0; mt < MT; mt++) {
#pragma unroll
        for (int nt = 0; nt < NT; nt++) {
#pragma unroll
            for (int r = 0; r < 4; r++) {
                int m = m0 + wm + mt * 16 + quad * 4 + r;
                int n = n0 + wn + nt * 16 + l16;
                float v = acc[mt][nt][r];
                if constexpr (MODE == 0) {
                    int bb = m >> 11, t = m & 2047;
                    int h = n >> 6, dh = n & 63;
                    size_t idx;
                    if (z == 2)   // V stored transposed: (b,h,dh,t)
                        idx = (((size_t)2 * BB * HH + bb * HH + h) * DHD + dh) * TT + t;
                    else
                        idx = (((size_t)z * BB * HH + bb * HH + h) * TT + t) * DHD + dh;
                    ((u16*)outp)[idx] = f2bf(v);
                } else {
                    ((float*)outp)[(size_t)m * DD + n] = v;
                }
            }
        }
    }
}

// ---------------- flash attention: 32x32 MFMA, split-KV, in-register P ----------------
// One block per (bh, 128 q-rows). 8 waves = 4 q-blocks(32 rows) x 2 kv-groups.
// Per round: stage 2 KV tiles (identical staging to verified kernel); group g
// computes its tile. QK^T as S^T = K.Q^T with 32x32x16 MFMA: C layout gives
// lane its FULL 32-kv P row for q=lane&31 (T12/HK structure) -> PV A-frags
// are rebuilt in-register (truncating packs + one shfl_xor(32) half-exchange)
// -> ZERO P LDS traffic, and 32x32 frags halve LDS bytes/FLOP for K and V.
// Group-combine epilogue + pair-balanced qt as in the verified R0 kernel.
__global__ __launch_bounds__(512, 2) void attn_k(const u16* __restrict__ QKV,
                                                 u16* __restrict__ AO) {
    const u16* Q  = QKV;
    const u16* Kp = QKV + (size_t)MM * DD;
    const u16* Vp = QKV + (size_t)2 * MM * DD;   // V^T: per head [DHD][TT]
    int bh = blockIdx.x;
    int by = blockIdx.y;
    int qt = (by < 8) ? (15 - by) : (by - 8);    // pair-balanced dispatch
    size_t hoff = (size_t)bh * TT * DHD;

    __shared__ u16 Ks[2][2][64 * 64];    // 32 KB [dbuf][tile]
    __shared__ u16 VTs[2][2][64 * 64];   // 32 KB

    int tid = threadIdx.x;
    int lane = tid & 63, wv = tid >> 6;
    int g = wv >> 2, w4 = wv & 3;        // kv-group, q 32-row block
    int l31 = lane & 31, hi = lane >> 5;
    int swz = l31 & 7;

    // staging: one 16B chunk per thread per 64x64 tile (identical to verified)
    int sr = tid >> 3, sc = tid & 7;
    int sl = sr * 64 + ((sc ^ (sr & 7)) * 8);
    const u16* gK = Kp + hoff + (size_t)sr * DHD + sc * 8;
    const u16* gV = Vp + hoff + (size_t)sr * TT + sc * 8;

    // Q B-frags direct from global (col=q=lane&31, k=8*hi+16*kt+e), scaled
    const float qscale = 0.125f * 1.4426950408889634f;
    int q0 = qt * 128;
    short8 qB[4];
    {
        const u16* gq = Q + hoff + (size_t)(q0 + w4 * 32 + l31) * DHD + hi * 8;
#pragma unroll
        for (int kt = 0; kt < 4; kt++) {
            short8 v = *(const short8*)(gq + 16 * kt);
            short8 sv;
#pragma unroll
            for (int e = 0; e < 8; e++) sv[e] = (short)f2bf(bf2f((u16)v[e]) * qscale);
            qB[kt] = sv;
        }
    }

    // prefetch round-0 KV tiles
    short8 prK[2], prV[2];
    prK[0] = *(const short8*)gK;
    prK[1] = *(const short8*)(gK + (size_t)64 * DHD);
    prV[0] = *(const short8*)gV;
    prV[1] = *(const short8*)(gV + 64);

    const int NR = qt + 1;   // round jt stages kv tiles 2jt, 2jt+1

    f32x16 o0 = (f32x16)(0.0f), o1 = (f32x16)(0.0f);
    float lr = 0.0f;

#pragma unroll 1
    for (int jt = 0; jt < NR; jt++) {
        int db = jt & 1;
#pragma unroll
        for (int tt = 0; tt < 2; tt++) {
            *(short8*)&Ks[db][tt][sl]  = prK[tt];
            *(short8*)&VTs[db][tt][sl] = prV[tt];
        }
        __syncthreads();

        if (jt + 1 < NR) {
            size_t nj = (size_t)(jt + 1) * 128;
            prK[0] = *(const short8*)(gK + nj * DHD);
            prK[1] = *(const short8*)(gK + (nj + 64) * DHD);
            prV[0] = *(const short8*)(gV + nj);
            prV[1] = *(const short8*)(gV + nj + 64);
        }

        // ---- S^T = K.Q^T (own tile g): lane&31 = q, regs = kv ----
        f32x16 s0 = (f32x16)(0.0f), s1 = (f32x16)(0.0f);
#pragma unroll
        for (int kt = 0; kt < 4; kt++) {
            int ch = ((hi + 2 * kt) ^ swz) * 8;
            short8 ak0 = *(const short8*)&Ks[db][g][l31 * 64 + ch];
            short8 ak1 = *(const short8*)&Ks[db][g][(32 + l31) * 64 + ch];
            s0 = __builtin_amdgcn_mfma_f32_32x32x16_bf16(ak0, qB[kt], s0, 0, 0, 0);
            s1 = __builtin_amdgcn_mfma_f32_32x32x16_bf16(ak1, qB[kt], s1, 0, 0, 0);
        }

        if (jt == qt) {   // diagonal round: mask kv > q (both tiles partial)
            int lim = w4 * 32 + l31 - g * 64;
#pragma unroll
            for (int r = 0; r < 16; r++) {
                int kvl = (r & 3) + 8 * (r >> 2) + 4 * hi;
                if (kvl > lim) s0[r] = -30000.0f;
                if (32 + kvl > lim) s1[r] = -30000.0f;
            }
        }

        // p = exp2(s) in place; rowsum
#pragma unroll
        for (int r = 0; r < 16; r++) {
            s0[r] = __builtin_amdgcn_exp2f(s0[r]);
            s1[r] = __builtin_amdgcn_exp2f(s1[r]);
            lr += s0[r] + s1[r];
        }

        // ---- build PV A-frags in-register (kv chunk = 16*kt2 + 8*hi + e) ----
        short8 pa[4];
#pragma unroll
        for (int kt2 = 0; kt2 < 4; kt2++) {
            f32x16 ps = (kt2 < 2) ? s0 : s1;
            const int base = 8 * (kt2 & 1);
            float e0 = ps[base + 0], e1 = ps[base + 1];
            float e2 = ps[base + 2], e3 = ps[base + 3];
            float e4 = ps[base + 4], e5 = ps[base + 5];
            float e6 = ps[base + 6], e7 = ps[base + 7];
            unsigned lA = packtr(e0, e1), lB = packtr(e2, e3);
            unsigned hA = packtr(e4, e5), hB = packtr(e6, e7);
            unsigned wA = hi ? hA : lA, wB = hi ? hB : lB;   // own half (t=hi)
            unsigned sA = hi ? lA : hA, sB = hi ? lB : hB;   // for partner (t=hi^1)
            unsigned rA = (unsigned)__shfl_xor((int)sA, 32);
            unsigned rB = (unsigned)__shfl_xor((int)sB, 32);
            union { unsigned w[4]; short8 v; } u;
            u.w[0] = hi ? rA : wA; u.w[1] = hi ? rB : wB;
            u.w[2] = hi ? wA : rA; u.w[3] = hi ? wB : rB;
            pa[kt2] = u.v;
        }

        // ---- PV: o(32q x 64d), B = V^T rows d, k chunk = hi + 2*kt2 ----
#pragma unroll
        for (int kt2 = 0; kt2 < 4; kt2++) {
            int ch = ((hi + 2 * kt2) ^ swz) * 8;
            short8 bv0 = *(const short8*)&VTs[db][g][l31 * 64 + ch];
            short8 bv1 = *(const short8*)&VTs[db][g][(32 + l31) * 64 + ch];
            o0 = __builtin_amdgcn_mfma_f32_32x32x16_bf16(pa[kt2], bv0, o0, 0, 0, 0);
            o1 = __builtin_amdgcn_mfma_f32_32x32x16_bf16(pa[kt2], bv1, o1, 0, 0, 0);
        }
    }

    // ---- combine group partials (sums are linear), normalize, store ----
    __syncthreads();
    float* Of = (float*)&Ks[0][0][0];    // [w4][dt][r][lane] = 32 KB
    float* Lf = (float*)&VTs[0][0][0];   // [w4][lane] = 1 KB
    if (g == 1) {
#pragma unroll
        for (int r = 0; r < 16; r++) {
            Of[((w4 * 2 + 0) * 16 + r) * 64 + lane] = o0[r];
            Of[((w4 * 2 + 1) * 16 + r) * 64 + lane] = o1[r];
        }
        Lf[w4 * 64 + lane] = lr;
    }
    __syncthreads();
    if (g == 0) {
#pragma unroll
        for (int r = 0; r < 16; r++) {
            o0[r] += Of[((w4 * 2 + 0) * 16 + r) * 64 + lane];
            o1[r] += Of[((w4 * 2 + 1) * 16 + r) * 64 + lane];
        }
        lr += Lf[w4 * 64 + lane];

        float rs = lr + __shfl_xor(lr, 32);   // full rowsum for q = lane&31

        int b = bh >> 4, h = bh & 15;
#pragma unroll
        for (int r = 0; r < 16; r++) {
            int qlc = (r & 3) + 8 * (r >> 2) + 4 * hi;   // q row of this reg
            float ri = 1.0f / __shfl(rs, qlc);
            int q = q0 + w4 * 32 + qlc;
            size_t rb = (size_t)(b * TT + q) * DD + h * 64 + l31;
            AO[rb]      = f2bf(o0[r] * ri);
            AO[rb + 32] = f2bf(o1[r] * ri);
        }
    }
}

extern "C" void kernel_launch(void* const* d_in, const int* in_sizes, int n_in,
                              void* d_out, int out_size, void* d_ws, size_t ws_size,
                              hipStream_t stream) {
    const float* x  = (const float*)d_in[0];
    const float* Wq = (const float*)d_in[1];
    const float* Wk = (const float*)d_in[2];
    const float* Wv = (const float*)d_in[3];
    const float* Wo = (const float*)d_in[4];

    u16* xb  = (u16*)d_ws;                       // 8 MB  : x in bf16
    u16* WT  = xb + (size_t)MM * DD;             // 8 MB  : 4 transposed weights bf16
    u16* QKV = WT + (size_t)4 * DD * DD;         // 24 MB : Q,K (b,h,t,dh) + V^T (b,h,dh,t)
    u16* AO  = QKV + (size_t)3 * MM * DD;        // 8 MB  : attention out (B,T,D) bf16
    float* out = (float*)d_out;

    prep_k<<<dim3(32, 32, 5), 256, 0, stream>>>(x, Wq, Wk, Wv, Wo, xb, WT);
    gemm_k<0, 128, 128, 64><<<dim3(DD / 128, MM / 128, 3), 256, 0, stream>>>(xb, WT, QKV);
    attn_k<<<dim3(32, 16), 512, 0, stream>>>(QKV, AO);
    gemm_k<1, 64, 128, 64><<<dim3(DD / 128, MM / 64, 1), 256, 0, stream>>>(AO, WT + (size_t)3 * DD * DD, out);
}

// Round 5
// 171.811 us; speedup vs baseline: 1.0216x; 1.0216x over previous
//
#include <hip/hip_runtime.h>

#define BB 2
#define TT 2048
#define DD 1024
#define HH 16
#define DHD 64
#define MM (BB*TT)   // 4096

typedef __attribute__((ext_vector_type(8))) short short8;
typedef __attribute__((ext_vector_type(4))) float float4v;
typedef __attribute__((ext_vector_type(16))) float f32x16;
typedef unsigned short u16;

__device__ inline float bf2f(u16 u) {
    union { unsigned int i; float f; } v;
    v.i = ((unsigned int)u) << 16;
    return v.f;
}
__device__ inline u16 f2bf(float f) {
    union { float f; unsigned int i; } v;
    v.f = f;
    unsigned int x = v.i;
    unsigned int r = (x + 0x7fffu + ((x >> 16) & 1u)) >> 16;
    return (u16)r;
}
// truncating bf16 pair-pack (bit-identical to the old P-store path)
__device__ inline unsigned packtr(float x, float y) {
    union { float f; unsigned u; } a, b;
    a.f = x; b.f = y;
    return (a.u >> 16) | (b.u & 0xffff0000u);
}

// async 16B global->LDS (DMA, no VGPR round-trip)
__device__ inline void gl_lds16(const u16* g, u16* l) {
    __builtin_amdgcn_global_load_lds(
        (const __attribute__((address_space(1))) unsigned int*)g,
        (__attribute__((address_space(3))) unsigned int*)l, 16, 0, 0);
}

// ---------------- prep: fused x-cast (z==4) + weight cast/transpose (z<4) ----------------
__global__ __launch_bounds__(256) void prep_k(const float* __restrict__ x,
                                              const float* __restrict__ Wq,
                                              const float* __restrict__ Wk,
                                              const float* __restrict__ Wv,
                                              const float* __restrict__ Wo,
                                              u16* __restrict__ xb,
                                              u16* __restrict__ WT) {
    int tid = threadIdx.x;
    if (blockIdx.z == 4) {   // cast x: 1024 blocks x 1024 float4
        int bid = blockIdx.y * 32 + blockIdx.x;
#pragma unroll
        for (int k = 0; k < 4; k++) {
            int i = bid * 1024 + k * 256 + tid;
            float4v v = ((const float4v*)x)[i];
            ushort4 o;
            o.x = f2bf(v[0]); o.y = f2bf(v[1]); o.z = f2bf(v[2]); o.w = f2bf(v[3]);
            ((ushort4*)xb)[i] = o;
        }
        return;
    }
    __shared__ u16 t[32][33];
    int wsel = blockIdx.z;
    const float* W = (wsel == 0) ? Wq : (wsel == 1) ? Wk : (wsel == 2) ? Wv : Wo;
    u16* o = WT + (size_t)wsel * DD * DD;
    int k0 = blockIdx.y * 32, n0 = blockIdx.x * 32;
    int tx = tid & 31, ty = tid >> 5;   // 32 x 8
#pragma unroll
    for (int i = 0; i < 4; i++) {
        int k = ty + i * 8;
        t[k][tx] = f2bf(W[(size_t)(k0 + k) * DD + n0 + tx]);
    }
    __syncthreads();
#pragma unroll
    for (int i = 0; i < 4; i++) {
        int n = ty + i * 8;
        o[(size_t)(n0 + n) * DD + k0 + tx] = t[tx][n];
    }
}

// ---------------- GEMM: global_load_lds staging (m97 structure) ----------------
template <int MODE, int TM, int TN, int BK>
__global__ __launch_bounds__(256) void gemm_k(const u16* __restrict__ A,
                                              const u16* __restrict__ WT0,
                                              void* __restrict__ outp) {
    const int K = DD;
    const int MT = TM / 32, NT = TN / 32;
    const int NS = (TM + TN) * (BK / 8) / 256;
    const int CPR = BK / 8;

    int z = blockIdx.z;
    const u16* WT = WT0 + (size_t)z * DD * DD;
    int n0 = blockIdx.x * TN, m0 = blockIdx.y * TM;

    __shared__ u16 S[(TM + TN) * BK];

    int tid = threadIdx.x;
    int lane = tid & 63, w = tid >> 6;
    int wm = (w >> 1) * (TM / 2), wn = (w & 1) * (TN / 2);
    int quad = lane >> 4, l16 = lane & 15;

    const u16* gp[NS];
    u16* lp[NS];
#pragma unroll
    for (int j = 0; j < NS; j++) {
        int cid = tid + j * 256;
        int r = cid / CPR, c = cid % CPR;
        lp[j] = S + (size_t)cid * 8;                      // linear LDS dest
        gp[j] = (r < TM ? A + (size_t)(m0 + r) * K
                        : WT + (size_t)(n0 + r - TM) * K) + ((c ^ (r & 7)) * 8);
    }
    int swz = l16 & 7;

    float4v acc[MT][NT];
#pragma unroll
    for (int i = 0; i < MT; i++)
#pragma unroll
        for (int j = 0; j < NT; j++) acc[i][j] = (float4v)(0.0f);

    const int NK = K / BK;
#pragma unroll 1
    for (int ki = 0; ki < NK; ki++) {
        __syncthreads();    // prev compute's S reads done
#pragma unroll
        for (int j = 0; j < NS; j++)
            gl_lds16(gp[j] + ki * BK, lp[j]);
        __syncthreads();    // barrier drain (vmcnt 0) publishes S

#pragma unroll
        for (int ks = 0; ks < BK / 32; ks++) {
            int cq = ((ks * 4 + quad) ^ swz) * 8;
            short8 a[MT], b[NT];
#pragma unroll
            for (int mt = 0; mt < MT; mt++)
                a[mt] = *(const short8*)&S[(wm + mt * 16 + l16) * BK + cq];
#pragma unroll
            for (int nt = 0; nt < NT; nt++)
                b[nt] = *(const short8*)&S[(TM + wn + nt * 16 + l16) * BK + cq];
#pragma unroll
            for (int mt = 0; mt < MT; mt++)
#pragma unroll
                for (int nt = 0; nt < NT; nt++)
                    acc[mt][nt] = __builtin_amdgcn_mfma_f32_16x16x32_bf16(
                        a[mt], b[nt], acc[mt][nt], 0, 0, 0);
        }
    }

#pragma unroll
    for (int mt = 0; mt < MT; mt++) {
#pragma unroll
        for (int nt = 0; nt < NT; nt++) {
#pragma unroll
            for (int r = 0; r < 4; r++) {
                int m = m0 + wm + mt * 16 + quad * 4 + r;
                int n = n0 + wn + nt * 16 + l16;
                float v = acc[mt][nt][r];
                if constexpr (MODE == 0) {
                    int bb = m >> 11, t = m & 2047;
                    int h = n >> 6, dh = n & 63;
                    size_t idx;
                    if (z == 2)   // V stored transposed: (b,h,dh,t)
                        idx = (((size_t)2 * BB * HH + bb * HH + h) * DHD + dh) * TT + t;
                    else
                        idx = (((size_t)z * BB * HH + bb * HH + h) * TT + t) * DHD + dh;
                    ((u16*)outp)[idx] = f2bf(v);
                } else {
                    ((float*)outp)[(size_t)m * DD + n] = v;
                }
            }
        }
    }
}

// ---------------- flash attention: 32x32 MFMA, split-KV, in-register P ----------------
// One block per (bh, 128 q-rows). 8 waves = 4 q-blocks(32 rows) x 2 kv-groups.
// QK^T as S^T = K.Q^T with 32x32x16 MFMA (lane owns full 32-kv P row, T12);
// PV A-frags rebuilt in-register (packs + shfl_xor(32)) -> zero P LDS traffic.
// R5 change: qt mapping balanced under BOTH consecutive (d,d+1) and strided
// (d,d+256) CU-pairing: qt = ((bx^(by>>3))&1) ? 15-(by&7) : (by&7).
// R4's map was only balanced under strided pairing; with 512 blocks filling
// exactly 512 residency slots (no backfill), a consecutive-pairing scheduler
// gives (15,15)/(0,0) CU pairs -> ~1.9x makespan. This map sums to 15 under
// both pairings. Per-head qt bijective; bh=bx keeps head on one XCD.
__global__ __launch_bounds__(512, 2) void attn_k(const u16* __restrict__ QKV,
                                                 u16* __restrict__ AO) {
    const u16* Q  = QKV;
    const u16* Kp = QKV + (size_t)MM * DD;
    const u16* Vp = QKV + (size_t)2 * MM * DD;   // V^T: per head [DHD][TT]
    int bx = blockIdx.x, by = blockIdx.y;
    int bh = bx;
    int t_ = by & 7, s_ = by >> 3;
    int qt = ((bx ^ s_) & 1) ? (15 - t_) : t_;   // dual-pairing-balanced
    size_t hoff = (size_t)bh * TT * DHD;

    __shared__ u16 Ks[2][2][64 * 64];    // 32 KB [dbuf][tile]
    __shared__ u16 VTs[2][2][64 * 64];   // 32 KB

    int tid = threadIdx.x;
    int lane = tid & 63, wv = tid >> 6;
    int g = wv >> 2, w4 = wv & 3;        // kv-group, q 32-row block
    int l31 = lane & 31, hi = lane >> 5;
    int swz = l31 & 7;

    // staging: one 16B chunk per thread per 64x64 tile (identical to verified)
    int sr = tid >> 3, sc = tid & 7;
    int sl = sr * 64 + ((sc ^ (sr & 7)) * 8);
    const u16* gK = Kp + hoff + (size_t)sr * DHD + sc * 8;
    const u16* gV = Vp + hoff + (size_t)sr * TT + sc * 8;

    // Q B-frags direct from global (col=q=lane&31, k=8*hi+16*kt+e), scaled
    const float qscale = 0.125f * 1.4426950408889634f;
    int q0 = qt * 128;
    short8 qB[4];
    {
        const u16* gq = Q + hoff + (size_t)(q0 + w4 * 32 + l31) * DHD + hi * 8;
#pragma unroll
        for (int kt = 0; kt < 4; kt++) {
            short8 v = *(const short8*)(gq + 16 * kt);
            short8 sv;
#pragma unroll
            for (int e = 0; e < 8; e++) sv[e] = (short)f2bf(bf2f((u16)v[e]) * qscale);
            qB[kt] = sv;
        }
    }

    // prefetch round-0 KV tiles
    short8 prK[2], prV[2];
    prK[0] = *(const short8*)gK;
    prK[1] = *(const short8*)(gK + (size_t)64 * DHD);
    prV[0] = *(const short8*)gV;
    prV[1] = *(const short8*)(gV + 64);

    const int NR = qt + 1;   // round jt stages kv tiles 2jt, 2jt+1

    f32x16 o0 = (f32x16)(0.0f), o1 = (f32x16)(0.0f);
    float lr = 0.0f;

#pragma unroll 1
    for (int jt = 0; jt < NR; jt++) {
        int db = jt & 1;
#pragma unroll
        for (int tt = 0; tt < 2; tt++) {
            *(short8*)&Ks[db][tt][sl]  = prK[tt];
            *(short8*)&VTs[db][tt][sl] = prV[tt];
        }
        __syncthreads();

        if (jt + 1 < NR) {
            size_t nj = (size_t)(jt + 1) * 128;
            prK[0] = *(const short8*)(gK + nj * DHD);
            prK[1] = *(const short8*)(gK + (nj + 64) * DHD);
            prV[0] = *(const short8*)(gV + nj);
            prV[1] = *(const short8*)(gV + nj + 64);
        }

        // ---- S^T = K.Q^T (own tile g): lane&31 = q, regs = kv ----
        f32x16 s0 = (f32x16)(0.0f), s1 = (f32x16)(0.0f);
#pragma unroll
        for (int kt = 0; kt < 4; kt++) {
            int ch = ((hi + 2 * kt) ^ swz) * 8;
            short8 ak0 = *(const short8*)&Ks[db][g][l31 * 64 + ch];
            short8 ak1 = *(const short8*)&Ks[db][g][(32 + l31) * 64 + ch];
            s0 = __builtin_amdgcn_mfma_f32_32x32x16_bf16(ak0, qB[kt], s0, 0, 0, 0);
            s1 = __builtin_amdgcn_mfma_f32_32x32x16_bf16(ak1, qB[kt], s1, 0, 0, 0);
        }

        if (jt == qt) {   // diagonal round: mask kv > q (both tiles partial)
            int lim = w4 * 32 + l31 - g * 64;
#pragma unroll
            for (int r = 0; r < 16; r++) {
                int kvl = (r & 3) + 8 * (r >> 2) + 4 * hi;
                if (kvl > lim) s0[r] = -30000.0f;
                if (32 + kvl > lim) s1[r] = -30000.0f;
            }
        }

        // p = exp2(s) in place; rowsum
#pragma unroll
        for (int r = 0; r < 16; r++) {
            s0[r] = __builtin_amdgcn_exp2f(s0[r]);
            s1[r] = __builtin_amdgcn_exp2f(s1[r]);
            lr += s0[r] + s1[r];
        }

        // ---- build PV A-frags in-register (kv chunk = 16*kt2 + 8*hi + e) ----
        short8 pa[4];
#pragma unroll
        for (int kt2 = 0; kt2 < 4; kt2++) {
            f32x16 ps = (kt2 < 2) ? s0 : s1;
            const int base = 8 * (kt2 & 1);
            float e0 = ps[base + 0], e1 = ps[base + 1];
            float e2 = ps[base + 2], e3 = ps[base + 3];
            float e4 = ps[base + 4], e5 = ps[base + 5];
            float e6 = ps[base + 6], e7 = ps[base + 7];
            unsigned lA = packtr(e0, e1), lB = packtr(e2, e3);
            unsigned hA = packtr(e4, e5), hB = packtr(e6, e7);
            unsigned wA = hi ? hA : lA, wB = hi ? hB : lB;   // own half (t=hi)
            unsigned sA = hi ? lA : hA, sB = hi ? lB : hB;   // for partner (t=hi^1)
            unsigned rA = (unsigned)__shfl_xor((int)sA, 32);
            unsigned rB = (unsigned)__shfl_xor((int)sB, 32);
            union { unsigned w[4]; short8 v; } u;
            u.w[0] = hi ? rA : wA; u.w[1] = hi ? rB : wB;
            u.w[2] = hi ? wA : rA; u.w[3] = hi ? wB : rB;
            pa[kt2] = u.v;
        }

        // ---- PV: o(32q x 64d), B = V^T rows d, k chunk = hi + 2*kt2 ----
#pragma unroll
        for (int kt2 = 0; kt2 < 4; kt2++) {
            int ch = ((hi + 2 * kt2) ^ swz) * 8;
            short8 bv0 = *(const short8*)&VTs[db][g][l31 * 64 + ch];
            short8 bv1 = *(const short8*)&VTs[db][g][(32 + l31) * 64 + ch];
            o0 = __builtin_amdgcn_mfma_f32_32x32x16_bf16(pa[kt2], bv0, o0, 0, 0, 0);
            o1 = __builtin_amdgcn_mfma_f32_32x32x16_bf16(pa[kt2], bv1, o1, 0, 0, 0);
        }
    }

    // ---- combine group partials (sums are linear), normalize, store ----
    __syncthreads();
    float* Of = (float*)&Ks[0][0][0];    // [w4][dt][r][lane] = 32 KB
    float* Lf = (float*)&VTs[0][0][0];   // [w4][lane] = 1 KB
    if (g == 1) {
#pragma unroll
        for (int r = 0; r < 16; r++) {
            Of[((w4 * 2 + 0) * 16 + r) * 64 + lane] = o0[r];
            Of[((w4 * 2 + 1) * 16 + r) * 64 + lane] = o1[r];
        }
        Lf[w4 * 64 + lane] = lr;
    }
    __syncthreads();
    if (g == 0) {
#pragma unroll
        for (int r = 0; r < 16; r++) {
            o0[r] += Of[((w4 * 2 + 0) * 16 + r) * 64 + lane];
            o1[r] += Of[((w4 * 2 + 1) * 16 + r) * 64 + lane];
        }
        lr += Lf[w4 * 64 + lane];

        float rs = lr + __shfl_xor(lr, 32);   // full rowsum for q = lane&31

        int b = bh >> 4, h = bh & 15;
#pragma unroll
        for (int r = 0; r < 16; r++) {
            int qlc = (r & 3) + 8 * (r >> 2) + 4 * hi;   // q row of this reg
            float ri = 1.0f / __shfl(rs, qlc);
            int q = q0 + w4 * 32 + qlc;
            size_t rb = (size_t)(b * TT + q) * DD + h * 64 + l31;
            AO[rb]      = f2bf(o0[r] * ri);
            AO[rb + 32] = f2bf(o1[r] * ri);
        }
    }
}

extern "C" void kernel_launch(void* const* d_in, const int* in_sizes, int n_in,
                              void* d_out, int out_size, void* d_ws, size_t ws_size,
                              hipStream_t stream) {
    const float* x  = (const float*)d_in[0];
    const float* Wq = (const float*)d_in[1];
    const float* Wk = (const float*)d_in[2];
    const float* Wv = (const float*)d_in[3];
    const float* Wo = (const float*)d_in[4];

    u16* xb  = (u16*)d_ws;                       // 8 MB  : x in bf16
    u16* WT  = xb + (size_t)MM * DD;             // 8 MB  : 4 transposed weights bf16
    u16* QKV = WT + (size_t)4 * DD * DD;         // 24 MB : Q,K (b,h,t,dh) + V^T (b,h,dh,t)
    u16* AO  = QKV + (size_t)3 * MM * DD;        // 8 MB  : attention out (B,T,D) bf16
    float* out = (float*)d_out;

    prep_k<<<dim3(32, 32, 5), 256, 0, stream>>>(x, Wq, Wk, Wv, Wo, xb, WT);
    gemm_k<0, 128, 128, 64><<<dim3(DD / 128, MM / 128, 3), 256, 0, stream>>>(xb, WT, QKV);
    attn_k<<<dim3(32, 16), 512, 0, stream>>>(QKV, AO);
    gemm_k<1, 64, 128, 64><<<dim3(DD / 128, MM / 64, 1), 256, 0, stream>>>(AO, WT + (size_t)3 * DD * DD, out);
}